// Round 4
// baseline (371.060 us; speedup 1.0000x reference)
//
#include <hip/hip_runtime.h>

// PointNetSaModule fused kernel — f32 in/out, f16 MFMA compute.
// R4 changes: W2 B-frags moved to block-shared LDS (frees ~64 VGPRs; unified
// VGPR/AGPR file made register footprint the occupancy cap), layer-0 bias
// folded into the zero-pad channel (ch67=1.0, W0 row67=t0 — free), single
// reused per-wave X buffer (DS ops in-order per wave -> WAR safe),
// __launch_bounds__(256,3). Gather lands directly in MFMA A-frags; depth-1
// software pipeline (nidx depth-2); pts pre-converted f32->f16 in d_ws.

#define NPT_     16384
#define OUTHALF_ 8388608      // elements: second output copy offset
#define XS_      72           // padded f16 stride of X rows (need 64)
#define W2S_     72           // padded f16 stride of W2' rows (need 64)
#define EPS_     1e-5f
#define GRID_    1024
#define NIT_     (NPT_ / GRID_)   // 16

typedef _Float16 h8    __attribute__((ext_vector_type(8)));
typedef float    f32x4 __attribute__((ext_vector_type(4)));

__global__ __launch_bounds__(256) void cvt_pts_kernel(
    const float* __restrict__ src, _Float16* __restrict__ dst)
{
    const size_t i = ((size_t)blockIdx.x * 256 + threadIdx.x) * 8;
    f32x4 a = *(const f32x4*)(src + i);
    f32x4 b = *(const f32x4*)(src + i + 4);
    h8 o;
#pragma unroll
    for (int j = 0; j < 4; ++j) { o[j] = (_Float16)a[j]; o[4 + j] = (_Float16)b[j]; }
    *(h8*)(dst + i) = o;
}

template<bool PRE>   // PRE: pts pre-converted to f16 in workspace
__global__ __launch_bounds__(256, 3) void pnsa_main(
    const float* __restrict__ xyz,    // (B,HW,3) f32
    const void*  __restrict__ ptsv,   // f16 ws if PRE, else f32 (B,HW,64)
    const float* __restrict__ xyzs,   // (B,NPT,3) f32
    const int*   __restrict__ nidx,   // (B,NPT*16)
    const float* __restrict__ vmask,  // (B,NPT,16) f32
    const float* __restrict__ w0, const float* __restrict__ b0,
    const float* __restrict__ g0, const float* __restrict__ be0,
    const float* __restrict__ m0, const float* __restrict__ v0,
    const float* __restrict__ w1, const float* __restrict__ b1,
    const float* __restrict__ g1, const float* __restrict__ be1,
    const float* __restrict__ m1, const float* __restrict__ v1,
    const float* __restrict__ w2, const float* __restrict__ b2,
    const float* __restrict__ g2, const float* __restrict__ be2,
    const float* __restrict__ m2, const float* __restrict__ v2,
    float*       __restrict__ out)
{
    __shared__ __align__(16) _Float16       ldsW2[128 * W2S_];  // W2'[n][k], BN-folded
    __shared__ __align__(16) float          s2sh[128];
    __shared__ __align__(16) unsigned short ldsX[4][16 * XS_];  // reused X1/X2 per wave

    const int tid  = threadIdx.x;
    const int wave = tid >> 6;
    const int lane = tid & 63;
    const int l15  = lane & 15;
    const int quad = lane >> 4;

    unsigned short* Xb = &ldsX[wave][0];

    // ---- stage s2 then W2' = diag(s2)-folded, transposed [n=out-ch][k=in-ch] ----
    if (tid < 128) s2sh[tid] = g2[tid] * rsqrtf(v2[tid] + EPS_);
    __syncthreads();
    for (int idx = tid; idx < 64 * 128; idx += 256) {          // coalesced over n
        const int k = idx >> 7, n = idx & 127;
        ldsW2[n * W2S_ + k] = (_Float16)(w2[idx] * s2sh[n]);
    }
    for (int idx = tid; idx < 128 * 8; idx += 256) {           // zero k-pad 64..71
        const int n = idx >> 3, k = 64 + (idx & 7);
        ldsW2[n * W2S_ + k] = (_Float16)0.f;
    }
    __syncthreads();

    // ---- BN-folded W0/W1 into register B-frags (f16), once per block ----
    // Feature k-order: [points 0..63, xyz_diff 64..66, BIAS 67 (=1.0), pad..95]
    // B-frag (16x16x32): lane holds B[k=quad*8+j][n=l15].
    h8    b0f[4][3], b1f[4][2];
    float t1r[4], t2r[8];

#pragma unroll
    for (int nt = 0; nt < 4; ++nt) {
        const int ch = nt * 16 + l15;
        const float s = g0[ch] * rsqrtf(v0[ch] + EPS_);
        const float t0 = (b0[ch] - m0[ch]) * s + be0[ch];
#pragma unroll
        for (int kk = 0; kk < 3; ++kk) {
            h8 f;
#pragma unroll
            for (int j = 0; j < 8; ++j) {
                const int k = kk * 32 + quad * 8 + j;
                float wv = 0.f;
                if (k < 64)       wv = w0[(3 + k) * 64 + ch] * s;
                else if (k < 67)  wv = w0[(k - 64) * 64 + ch] * s;
                else if (k == 67) wv = t0;                     // bias via 1.0 channel
                f[j] = (_Float16)wv;
            }
            b0f[nt][kk] = f;
        }
    }
#pragma unroll
    for (int nt = 0; nt < 4; ++nt) {
        const int ch = nt * 16 + l15;
        const float s = g1[ch] * rsqrtf(v1[ch] + EPS_);
        t1r[nt] = (b1[ch] - m1[ch]) * s + be1[ch];
#pragma unroll
        for (int kk = 0; kk < 2; ++kk) {
            h8 f;
#pragma unroll
            for (int j = 0; j < 8; ++j)
                f[j] = (_Float16)(w1[(kk * 32 + quad * 8 + j) * 64 + ch] * s);
            b1f[nt][kk] = f;
        }
    }
#pragma unroll
    for (int nt = 0; nt < 8; ++nt) {
        const int ch = nt * 16 + l15;
        t2r[nt] = (b2[ch] - m2[ch]) * s2sh[ch] + be2[ch];
    }

    // ---- pipelined load helpers ----
    auto issue_pts = [&](int p_, int nb_, h8& q0, h8& q1,
                         float& xga, float& xgb, float& xgc) {
        const size_t row = (size_t)(((p_ >> 14) << 16) + nb_);
        if constexpr (PRE) {
            const _Float16* pw = (const _Float16*)ptsv + (row << 6);
            q0 = *(const h8*)(pw + quad * 8);
            q1 = *(const h8*)(pw + 32 + quad * 8);
        }
        const float* xgp = xyz + row * 3;
        xga = xgp[0]; xgb = xgp[1]; xgc = xgp[2];
    };
    auto issue_aux = [&](int p_, float& xsa, float& xsb, float& xsc, float& mk) {
        mk = vmask[(p_ << 4) + l15];
        const float* xsp = xyzs + (size_t)p_ * 3;
        xsa = xsp[0]; xsb = xsp[1]; xsc = xsp[2];
    };

    // ---- prologue ----
    const int g = blockIdx.x;
    const int p0 = (g << 2) + wave;
    int nbc = nidx[(p0 << 4) + l15];
    h8 q0c, q1c;
    float xg0c, xg1c, xg2c, xs0c, xs1c, xs2c, mkc;
    issue_pts(p0, nbc, q0c, q1c, xg0c, xg1c, xg2c);
    issue_aux(p0, xs0c, xs1c, xs2c, mkc);
    const int g1i = (NIT_ > 1) ? g + GRID_ : g;
    int nbn = nidx[((((g1i << 2) + wave)) << 4) + l15];

    for (int it = 0; it < NIT_; ++it) {
        const int gcur = g + it * GRID_;
        const int pcur = (gcur << 2) + wave;
        const int gn   = (it + 1 < NIT_) ? gcur + GRID_ : gcur;
        const int pn   = (gn << 2) + wave;
        const int gn2  = (it + 2 < NIT_) ? gcur + 2 * GRID_ : gn;
        const int pn2  = (gn2 << 2) + wave;

        // issue next-iteration loads (overlap with current compute)
        h8 q0n, q1n;
        float xg0n, xg1n, xg2n, xs0n, xs1n, xs2n, mkn;
        issue_pts(pn, nbn, q0n, q1n, xg0n, xg1n, xg2n);
        issue_aux(pn, xs0n, xs1n, xs2n, mkn);
        const int nbn2 = nidx[(pn2 << 4) + l15];

        // ---- current point A-frags ----
        h8 a0, a1, a2;
        if constexpr (PRE) {
            a0 = q0c; a1 = q1c;
        } else {
            const size_t row = (size_t)(((pcur >> 14) << 16) + nbc);
            const float* pw = (const float*)ptsv + (row << 6);
            f32x4 r0 = *(const f32x4*)(pw + quad * 8);
            f32x4 r1 = *(const f32x4*)(pw + quad * 8 + 4);
            f32x4 r2 = *(const f32x4*)(pw + 32 + quad * 8);
            f32x4 r3 = *(const f32x4*)(pw + 32 + quad * 8 + 4);
#pragma unroll
            for (int j = 0; j < 4; ++j) {
                a0[j] = (_Float16)r0[j]; a0[4 + j] = (_Float16)r1[j];
                a1[j] = (_Float16)r2[j]; a1[4 + j] = (_Float16)r3[j];
            }
        }
        if (mkc == 0.0f) { a0 = (h8)(_Float16)0.f; a1 = (h8)(_Float16)0.f; }
        a2 = (h8)(_Float16)0.f;
        if (quad == 0) {
            a2[0] = (_Float16)(xg0c * mkc - xs0c);
            a2[1] = (_Float16)(xg1c * mkc - xs1c);
            a2[2] = (_Float16)(xg2c * mkc - xs2c);
            a2[3] = (_Float16)1.0f;               // bias channel (never masked)
        }

        // ---- layer 0: (16x96pad) @ (96x64), bias folded in ----
#pragma unroll
        for (int nt = 0; nt < 4; ++nt) {
            f32x4 acc = {0.f, 0.f, 0.f, 0.f};
            acc = __builtin_amdgcn_mfma_f32_16x16x32_f16(a0, b0f[nt][0], acc, 0, 0, 0);
            acc = __builtin_amdgcn_mfma_f32_16x16x32_f16(a1, b0f[nt][1], acc, 0, 0, 0);
            acc = __builtin_amdgcn_mfma_f32_16x16x32_f16(a2, b0f[nt][2], acc, 0, 0, 0);
#pragma unroll
            for (int r = 0; r < 4; ++r) {
                const _Float16 hv = (_Float16)fmaxf(acc[r], 0.f);
                Xb[(quad * 4 + r) * XS_ + nt * 16 + l15] = __builtin_bit_cast(unsigned short, hv);
            }
        }

        // ---- layer 1: (16x64) @ (64x64) ----
        h8 x0 = *(const h8*)(Xb + l15 * XS_ + quad * 8);
        h8 x1 = *(const h8*)(Xb + l15 * XS_ + 32 + quad * 8);
#pragma unroll
        for (int nt = 0; nt < 4; ++nt) {
            f32x4 acc = {0.f, 0.f, 0.f, 0.f};
            acc = __builtin_amdgcn_mfma_f32_16x16x32_f16(x0, b1f[nt][0], acc, 0, 0, 0);
            acc = __builtin_amdgcn_mfma_f32_16x16x32_f16(x1, b1f[nt][1], acc, 0, 0, 0);
#pragma unroll
            for (int r = 0; r < 4; ++r) {
                const _Float16 hv = (_Float16)fmaxf(acc[r] + t1r[nt], 0.f);
                // same buffer: DS ops are in-order per wave, reads above already issued
                Xb[(quad * 4 + r) * XS_ + nt * 16 + l15] = __builtin_bit_cast(unsigned short, hv);
            }
        }

        // ---- layer 2: (16x64) @ (64x128), W2 frags from LDS + K-maxpool ----
        h8 y0 = *(const h8*)(Xb + l15 * XS_ + quad * 8);
        h8 y1 = *(const h8*)(Xb + l15 * XS_ + 32 + quad * 8);
        float rm[8];
#pragma unroll
        for (int nt = 0; nt < 8; ++nt) {
            const _Float16* wrow = ldsW2 + (nt * 16 + l15) * W2S_;
            h8 wa = *(const h8*)(wrow + quad * 8);
            h8 wb = *(const h8*)(wrow + 32 + quad * 8);
            f32x4 acc = {0.f, 0.f, 0.f, 0.f};
            acc = __builtin_amdgcn_mfma_f32_16x16x32_f16(y0, wa, acc, 0, 0, 0);
            acc = __builtin_amdgcn_mfma_f32_16x16x32_f16(y1, wb, acc, 0, 0, 0);
            float v = 0.f;                       // relu(max) == max(relu, 0)
#pragma unroll
            for (int r = 0; r < 4; ++r) v = fmaxf(v, acc[r] + t2r[nt]);
            v = fmaxf(v, __shfl_xor(v, 16, 64));
            v = fmaxf(v, __shfl_xor(v, 32, 64));
            rm[nt] = v;                          // replicated across quads
        }
        // coalesced stores: lane writes channel ntg*64+lane -> needs rm[ntg*4+quad]
        float* ob = out + ((size_t)pcur << 7);
#pragma unroll
        for (int ntg = 0; ntg < 2; ++ntg) {
            const float s01 = (quad == 0) ? rm[ntg * 4 + 0] : rm[ntg * 4 + 1];
            const float s23 = (quad == 2) ? rm[ntg * 4 + 2] : rm[ntg * 4 + 3];
            const float vv  = (quad < 2) ? s01 : s23;
            ob[ntg * 64 + lane]            = vv;
            ob[OUTHALF_ + ntg * 64 + lane] = vv;
        }

        // ---- rotate pipeline ----
        nbc = nbn; nbn = nbn2;
        q0c = q0n; q1c = q1n;
        xg0c = xg0n; xg1c = xg1n; xg2c = xg2n;
        xs0c = xs0n; xs1c = xs1n; xs2c = xs2n;
        mkc = mkn;
    }
}

extern "C" void kernel_launch(void* const* d_in, const int* in_sizes, int n_in,
                              void* d_out, int out_size, void* d_ws, size_t ws_size,
                              hipStream_t stream) {
    const float* xyz   = (const float*)d_in[0];
    const float* pts   = (const float*)d_in[1];
    const float* xyzs  = (const float*)d_in[2];
    const int*   nidx  = (const int*)d_in[3];
    const float* vmask = (const float*)d_in[4];
    const float *w0 = (const float*)d_in[5],  *b0 = (const float*)d_in[6],
                *g0 = (const float*)d_in[7],  *be0 = (const float*)d_in[8],
                *m0 = (const float*)d_in[9],  *v0 = (const float*)d_in[10];
    const float *w1 = (const float*)d_in[11], *b1 = (const float*)d_in[12],
                *g1 = (const float*)d_in[13], *be1 = (const float*)d_in[14],
                *m1 = (const float*)d_in[15], *v1 = (const float*)d_in[16];
    const float *w2 = (const float*)d_in[17], *b2 = (const float*)d_in[18],
                *g2 = (const float*)d_in[19], *be2 = (const float*)d_in[20],
                *m2 = (const float*)d_in[21], *v2 = (const float*)d_in[22];
    float* outp = (float*)d_out;

    const size_t PTS_ELEMS = 16777216ull;           // 4*65536*64
    if (ws_size >= PTS_ELEMS * sizeof(_Float16)) {
        _Float16* ptsh = (_Float16*)d_ws;
        cvt_pts_kernel<<<dim3(8192), dim3(256), 0, stream>>>(pts, ptsh);
        pnsa_main<true><<<dim3(GRID_), dim3(256), 0, stream>>>(
            xyz, (const void*)ptsh, xyzs, nidx, vmask,
            w0, b0, g0, be0, m0, v0,
            w1, b1, g1, be1, m1, v1,
            w2, b2, g2, be2, m2, v2, outp);
    } else {
        pnsa_main<false><<<dim3(GRID_), dim3(256), 0, stream>>>(
            xyz, (const void*)pts, xyzs, nidx, vmask,
            w0, b0, g0, be0, m0, v0,
            w1, b1, g1, be1, m1, v1,
            w2, b2, g2, be2, m2, v2, outp);
    }
}

// Round 5
// 307.288 us; speedup vs baseline: 1.2075x; 1.2075x over previous
//
#include <hip/hip_runtime.h>

// PointNetSaModule fused — f32 in/out, f16 MFMA compute.
// R5: W1+W2 BN-folded weights in block-shared LDS (frees ~96 unified regs;
// R4 showed launch_bounds(256,3) + register-resident W1/W2 spills to scratch:
// FETCH 91->403 MB). W0 stays in register B-frags. Grid 768 = 3 blocks/CU
// (matches predicted residency at 3 waves/SIMD; avoids dispatch-round
// quantization). Dynamic trip count, depth-1/2 software pipeline, gather
// lands directly in MFMA A-frags, bias folded into layer-0 pad channel,
// fused K-maxpool epilogue with coalesced dual stores.

#define NPT_     16384
#define OUTHALF_ 8388608      // elements: second output copy offset
#define XS_      72           // padded f16 stride of X rows (need 64)
#define WS_      72           // padded f16 stride of W1'/W2' rows (need 64)
#define EPS_     1e-5f
#define GRID_    768          // 3 blocks/CU x 256 CUs

typedef _Float16 h8    __attribute__((ext_vector_type(8)));
typedef float    f32x4 __attribute__((ext_vector_type(4)));

__global__ __launch_bounds__(256) void cvt_pts_kernel(
    const float* __restrict__ src, _Float16* __restrict__ dst)
{
    const size_t i = ((size_t)blockIdx.x * 256 + threadIdx.x) * 8;
    f32x4 a = *(const f32x4*)(src + i);
    f32x4 b = *(const f32x4*)(src + i + 4);
    h8 o;
#pragma unroll
    for (int j = 0; j < 4; ++j) { o[j] = (_Float16)a[j]; o[4 + j] = (_Float16)b[j]; }
    *(h8*)(dst + i) = o;
}

template<bool PRE>   // PRE: pts pre-converted to f16 in workspace
__global__ __launch_bounds__(256, 3) void pnsa_main(
    const float* __restrict__ xyz,    // (B,HW,3) f32
    const void*  __restrict__ ptsv,   // f16 ws if PRE, else f32 (B,HW,64)
    const float* __restrict__ xyzs,   // (B,NPT,3) f32
    const int*   __restrict__ nidx,   // (B,NPT*16)
    const float* __restrict__ vmask,  // (B,NPT,16) f32
    const float* __restrict__ w0, const float* __restrict__ b0,
    const float* __restrict__ g0, const float* __restrict__ be0,
    const float* __restrict__ m0, const float* __restrict__ v0,
    const float* __restrict__ w1, const float* __restrict__ b1,
    const float* __restrict__ g1, const float* __restrict__ be1,
    const float* __restrict__ m1, const float* __restrict__ v1,
    const float* __restrict__ w2, const float* __restrict__ b2,
    const float* __restrict__ g2, const float* __restrict__ be2,
    const float* __restrict__ m2, const float* __restrict__ v2,
    float*       __restrict__ out)
{
    __shared__ __align__(16) _Float16       ldsW1[64 * WS_];    // W1'[n][k]
    __shared__ __align__(16) _Float16       ldsW2[128 * WS_];   // W2'[n][k]
    __shared__ __align__(16) float          s1sh[64];
    __shared__ __align__(16) float          s2sh[128];
    __shared__ __align__(16) unsigned short ldsX[4][16 * XS_];  // reused X1/X2, per wave

    const int tid  = threadIdx.x;
    const int wave = tid >> 6;
    const int lane = tid & 63;
    const int l15  = lane & 15;
    const int quad = lane >> 4;

    unsigned short* Xb = &ldsX[wave][0];

    // ---- stage BN scales, then W1'/W2' transposed+folded into LDS ----
    if (tid < 64)  s1sh[tid] = g1[tid] * rsqrtf(v1[tid] + EPS_);
    if (tid < 128) s2sh[tid] = g2[tid] * rsqrtf(v2[tid] + EPS_);
    __syncthreads();
    for (int idx = tid; idx < 64 * 64; idx += 256) {     // w1[k][n] -> W1'[n][k]
        const int k = idx >> 6, n = idx & 63;
        ldsW1[n * WS_ + k] = (_Float16)(w1[idx] * s1sh[n]);
    }
    for (int idx = tid; idx < 64 * 128; idx += 256) {    // w2[k][n] -> W2'[n][k]
        const int k = idx >> 7, n = idx & 127;
        ldsW2[n * WS_ + k] = (_Float16)(w2[idx] * s2sh[n]);
    }
    __syncthreads();

    // ---- W0 BN-folded into register B-frags; bias via pad channel 67 ----
    // Feature k-order: [points 0..63, xyz_diff 64..66, BIAS 67 (=1.0), pad..95]
    // B-frag (16x16x32): lane holds B[k=quad*8+j][n=l15].
    h8    b0f[4][3];
    float t1r[4], t2r[8];

#pragma unroll
    for (int nt = 0; nt < 4; ++nt) {
        const int ch = nt * 16 + l15;
        const float s = g0[ch] * rsqrtf(v0[ch] + EPS_);
        const float t0 = (b0[ch] - m0[ch]) * s + be0[ch];
#pragma unroll
        for (int kk = 0; kk < 3; ++kk) {
            h8 f;
#pragma unroll
            for (int j = 0; j < 8; ++j) {
                const int k = kk * 32 + quad * 8 + j;
                float wv = 0.f;
                if (k < 64)       wv = w0[(3 + k) * 64 + ch] * s;
                else if (k < 67)  wv = w0[(k - 64) * 64 + ch] * s;
                else if (k == 67) wv = t0;                 // bias via 1.0 channel
                f[j] = (_Float16)wv;
            }
            b0f[nt][kk] = f;
        }
    }
#pragma unroll
    for (int nt = 0; nt < 4; ++nt) {
        const int ch = nt * 16 + l15;
        t1r[nt] = (b1[ch] - m1[ch]) * s1sh[ch] + be1[ch];
    }
#pragma unroll
    for (int nt = 0; nt < 8; ++nt) {
        const int ch = nt * 16 + l15;
        t2r[nt] = (b2[ch] - m2[ch]) * s2sh[ch] + be2[ch];
    }

    // ---- pipelined load helpers ----
    auto issue_pts = [&](int p_, int nb_, h8& q0, h8& q1,
                         float& xga, float& xgb, float& xgc) {
        const size_t row = (size_t)(((p_ >> 14) << 16) + nb_);
        if constexpr (PRE) {
            const _Float16* pw = (const _Float16*)ptsv + (row << 6);
            q0 = *(const h8*)(pw + quad * 8);
            q1 = *(const h8*)(pw + 32 + quad * 8);
        }
        const float* xgp = xyz + row * 3;
        xga = xgp[0]; xgb = xgp[1]; xgc = xgp[2];
    };
    auto issue_aux = [&](int p_, float& xsa, float& xsb, float& xsc, float& mk) {
        mk = vmask[(p_ << 4) + l15];
        const float* xsp = xyzs + (size_t)p_ * 3;
        xsa = xsp[0]; xsb = xsp[1]; xsc = xsp[2];
    };

    // ---- prologue (dynamic trip count: g, g+GRID_, ... < NPT_) ----
    const int g = blockIdx.x;
    const int itc = ((NPT_ - 1 - g) / GRID_) + 1;
    const int p0 = (g << 2) + wave;
    int nbc = nidx[(p0 << 4) + l15];
    h8 q0c, q1c;
    float xg0c, xg1c, xg2c, xs0c, xs1c, xs2c, mkc;
    issue_pts(p0, nbc, q0c, q1c, xg0c, xg1c, xg2c);
    issue_aux(p0, xs0c, xs1c, xs2c, mkc);
    const int g1i = (itc > 1) ? g + GRID_ : g;
    int nbn = nidx[((((g1i << 2) + wave)) << 4) + l15];

    for (int it = 0; it < itc; ++it) {
        const int gcur = g + it * GRID_;
        const int pcur = (gcur << 2) + wave;
        const int gn   = (it + 1 < itc) ? gcur + GRID_ : gcur;
        const int pn   = (gn << 2) + wave;
        const int gn2  = (it + 2 < itc) ? gcur + 2 * GRID_ : gn;
        const int pn2  = (gn2 << 2) + wave;

        // issue next-iteration loads (overlap with current compute)
        h8 q0n, q1n;
        float xg0n, xg1n, xg2n, xs0n, xs1n, xs2n, mkn;
        issue_pts(pn, nbn, q0n, q1n, xg0n, xg1n, xg2n);
        issue_aux(pn, xs0n, xs1n, xs2n, mkn);
        const int nbn2 = nidx[(pn2 << 4) + l15];

        // ---- current point A-frags ----
        h8 a0, a1, a2;
        if constexpr (PRE) {
            a0 = q0c; a1 = q1c;
        } else {
            const size_t row = (size_t)(((pcur >> 14) << 16) + nbc);
            const float* pw = (const float*)ptsv + (row << 6);
            f32x4 r0 = *(const f32x4*)(pw + quad * 8);
            f32x4 r1 = *(const f32x4*)(pw + quad * 8 + 4);
            f32x4 r2 = *(const f32x4*)(pw + 32 + quad * 8);
            f32x4 r3 = *(const f32x4*)(pw + 32 + quad * 8 + 4);
#pragma unroll
            for (int j = 0; j < 4; ++j) {
                a0[j] = (_Float16)r0[j]; a0[4 + j] = (_Float16)r1[j];
                a1[j] = (_Float16)r2[j]; a1[4 + j] = (_Float16)r3[j];
            }
        }
        if (mkc == 0.0f) { a0 = (h8)(_Float16)0.f; a1 = (h8)(_Float16)0.f; }
        a2 = (h8)(_Float16)0.f;
        if (quad == 0) {
            a2[0] = (_Float16)(xg0c * mkc - xs0c);
            a2[1] = (_Float16)(xg1c * mkc - xs1c);
            a2[2] = (_Float16)(xg2c * mkc - xs2c);
            a2[3] = (_Float16)1.0f;               // bias channel (never masked)
        }

        // ---- layer 0: (16x96pad) @ (96x64), bias folded in ----
#pragma unroll
        for (int nt = 0; nt < 4; ++nt) {
            f32x4 acc = {0.f, 0.f, 0.f, 0.f};
            acc = __builtin_amdgcn_mfma_f32_16x16x32_f16(a0, b0f[nt][0], acc, 0, 0, 0);
            acc = __builtin_amdgcn_mfma_f32_16x16x32_f16(a1, b0f[nt][1], acc, 0, 0, 0);
            acc = __builtin_amdgcn_mfma_f32_16x16x32_f16(a2, b0f[nt][2], acc, 0, 0, 0);
#pragma unroll
            for (int r = 0; r < 4; ++r) {
                const _Float16 hv = (_Float16)fmaxf(acc[r], 0.f);
                Xb[(quad * 4 + r) * XS_ + nt * 16 + l15] = __builtin_bit_cast(unsigned short, hv);
            }
        }

        // ---- layer 1: (16x64) @ (64x64), W1 frags from LDS ----
        h8 x0 = *(const h8*)(Xb + l15 * XS_ + quad * 8);
        h8 x1 = *(const h8*)(Xb + l15 * XS_ + 32 + quad * 8);
#pragma unroll
        for (int nt = 0; nt < 4; ++nt) {
            const _Float16* wrow = ldsW1 + (nt * 16 + l15) * WS_;
            h8 wa = *(const h8*)(wrow + quad * 8);
            h8 wb = *(const h8*)(wrow + 32 + quad * 8);
            f32x4 acc = {0.f, 0.f, 0.f, 0.f};
            acc = __builtin_amdgcn_mfma_f32_16x16x32_f16(x0, wa, acc, 0, 0, 0);
            acc = __builtin_amdgcn_mfma_f32_16x16x32_f16(x1, wb, acc, 0, 0, 0);
#pragma unroll
            for (int r = 0; r < 4; ++r) {
                const _Float16 hv = (_Float16)fmaxf(acc[r] + t1r[nt], 0.f);
                // same buffer: DS ops in-order per wave, reads above already issued
                Xb[(quad * 4 + r) * XS_ + nt * 16 + l15] = __builtin_bit_cast(unsigned short, hv);
            }
        }

        // ---- layer 2: (16x64) @ (64x128), W2 frags from LDS + K-maxpool ----
        h8 y0 = *(const h8*)(Xb + l15 * XS_ + quad * 8);
        h8 y1 = *(const h8*)(Xb + l15 * XS_ + 32 + quad * 8);
        float rm[8];
#pragma unroll
        for (int nt = 0; nt < 8; ++nt) {
            const _Float16* wrow = ldsW2 + (nt * 16 + l15) * WS_;
            h8 wa = *(const h8*)(wrow + quad * 8);
            h8 wb = *(const h8*)(wrow + 32 + quad * 8);
            f32x4 acc = {0.f, 0.f, 0.f, 0.f};
            acc = __builtin_amdgcn_mfma_f32_16x16x32_f16(y0, wa, acc, 0, 0, 0);
            acc = __builtin_amdgcn_mfma_f32_16x16x32_f16(y1, wb, acc, 0, 0, 0);
            float v = 0.f;                       // relu(max) == max(relu, 0)
#pragma unroll
            for (int r = 0; r < 4; ++r) v = fmaxf(v, acc[r] + t2r[nt]);
            v = fmaxf(v, __shfl_xor(v, 16, 64));
            v = fmaxf(v, __shfl_xor(v, 32, 64));
            rm[nt] = v;                          // replicated across quads
        }
        // coalesced stores: lane writes channel ntg*64+lane -> needs rm[ntg*4+quad]
        float* ob = out + ((size_t)pcur << 7);
#pragma unroll
        for (int ntg = 0; ntg < 2; ++ntg) {
            const float s01 = (quad == 0) ? rm[ntg * 4 + 0] : rm[ntg * 4 + 1];
            const float s23 = (quad == 2) ? rm[ntg * 4 + 2] : rm[ntg * 4 + 3];
            const float vv  = (quad < 2) ? s01 : s23;
            ob[ntg * 64 + lane]            = vv;
            ob[OUTHALF_ + ntg * 64 + lane] = vv;
        }

        // ---- rotate pipeline ----
        nbc = nbn; nbn = nbn2;
        q0c = q0n; q1c = q1n;
        xg0c = xg0n; xg1c = xg1n; xg2c = xg2n;
        xs0c = xs0n; xs1c = xs1n; xs2c = xs2n;
        mkc = mkn;
    }
}

extern "C" void kernel_launch(void* const* d_in, const int* in_sizes, int n_in,
                              void* d_out, int out_size, void* d_ws, size_t ws_size,
                              hipStream_t stream) {
    const float* xyz   = (const float*)d_in[0];
    const float* pts   = (const float*)d_in[1];
    const float* xyzs  = (const float*)d_in[2];
    const int*   nidx  = (const int*)d_in[3];
    const float* vmask = (const float*)d_in[4];
    const float *w0 = (const float*)d_in[5],  *b0 = (const float*)d_in[6],
                *g0 = (const float*)d_in[7],  *be0 = (const float*)d_in[8],
                *m0 = (const float*)d_in[9],  *v0 = (const float*)d_in[10];
    const float *w1 = (const float*)d_in[11], *b1 = (const float*)d_in[12],
                *g1 = (const float*)d_in[13], *be1 = (const float*)d_in[14],
                *m1 = (const float*)d_in[15], *v1 = (const float*)d_in[16];
    const float *w2 = (const float*)d_in[17], *b2 = (const float*)d_in[18],
                *g2 = (const float*)d_in[19], *be2 = (const float*)d_in[20],
                *m2 = (const float*)d_in[21], *v2 = (const float*)d_in[22];
    float* outp = (float*)d_out;

    const size_t PTS_ELEMS = 16777216ull;           // 4*65536*64
    if (ws_size >= PTS_ELEMS * sizeof(_Float16)) {
        _Float16* ptsh = (_Float16*)d_ws;
        cvt_pts_kernel<<<dim3(8192), dim3(256), 0, stream>>>(pts, ptsh);
        pnsa_main<true><<<dim3(GRID_), dim3(256), 0, stream>>>(
            xyz, (const void*)ptsh, xyzs, nidx, vmask,
            w0, b0, g0, be0, m0, v0,
            w1, b1, g1, be1, m1, v1,
            w2, b2, g2, be2, m2, v2, outp);
    } else {
        pnsa_main<false><<<dim3(GRID_), dim3(256), 0, stream>>>(
            xyz, (const void*)pts, xyzs, nidx, vmask,
            w0, b0, g0, be0, m0, v0,
            w1, b1, g1, be1, m1, v1,
            w2, b2, g2, be2, m2, v2, outp);
    }
}

// Round 6
// 224.704 us; speedup vs baseline: 1.6513x; 1.3675x over previous
//
#include <hip/hip_runtime.h>

// PointNetSaModule fused — f32 in/out, f16 MFMA compute.
// R6: 2 points per wave per iteration (halves per-point LDS weight-frag
// traffic — R5 analysis: ~30 ds_read_b128/pt = ~48us LDS floor), layer-1/2
// nt-loops partially unrolled (unroll 2) with t-vectors in LDS and per-nt
// inline stores — kills the register-array full-unroll pressure that made
// (256,3) spill ~20 regs/iter (R4/R5: FETCH 403/460 MB). b0f stays in regs.
// W1/W2 BN-folded in block LDS. No pts-data prefetch (TLP hides latency);
// nidx prefetched depth-1. Grid 768 = 3 blocks/CU.

#define NGRP_    8192         // groups of 8 points (B*h*w/8)
#define OUTHALF_ 8388608      // elements: second output copy offset
#define XS_      72           // padded f16 stride of X rows (need 64)
#define WS_      72           // padded f16 stride of W1'/W2' rows (need 64)
#define EPS_     1e-5f
#define GRID_    768          // 3 blocks/CU x 256 CUs

typedef _Float16 h8    __attribute__((ext_vector_type(8)));
typedef float    f32x4 __attribute__((ext_vector_type(4)));

__global__ __launch_bounds__(256) void cvt_pts_kernel(
    const float* __restrict__ src, _Float16* __restrict__ dst)
{
    const size_t i = ((size_t)blockIdx.x * 256 + threadIdx.x) * 8;
    f32x4 a = *(const f32x4*)(src + i);
    f32x4 b = *(const f32x4*)(src + i + 4);
    h8 o;
#pragma unroll
    for (int j = 0; j < 4; ++j) { o[j] = (_Float16)a[j]; o[4 + j] = (_Float16)b[j]; }
    *(h8*)(dst + i) = o;
}

template<bool PRE>   // PRE: pts pre-converted to f16 in workspace
__global__ __launch_bounds__(256, 3) void pnsa_main(
    const float* __restrict__ xyz,    // (B,HW,3) f32
    const void*  __restrict__ ptsv,   // f16 ws if PRE, else f32 (B,HW,64)
    const float* __restrict__ xyzs,   // (B,NPT,3) f32
    const int*   __restrict__ nidx,   // (B,NPT*16)
    const float* __restrict__ vmask,  // (B,NPT,16) f32
    const float* __restrict__ w0, const float* __restrict__ b0,
    const float* __restrict__ g0, const float* __restrict__ be0,
    const float* __restrict__ m0, const float* __restrict__ v0,
    const float* __restrict__ w1, const float* __restrict__ b1,
    const float* __restrict__ g1, const float* __restrict__ be1,
    const float* __restrict__ m1, const float* __restrict__ v1,
    const float* __restrict__ w2, const float* __restrict__ b2,
    const float* __restrict__ g2, const float* __restrict__ be2,
    const float* __restrict__ m2, const float* __restrict__ v2,
    float*       __restrict__ out)
{
    __shared__ __align__(16) _Float16       ldsW1[64 * WS_];    // W1'[n][k]
    __shared__ __align__(16) _Float16       ldsW2[128 * WS_];   // W2'[n][k]
    __shared__ __align__(16) float          s1sh[64], t1sh[64];
    __shared__ __align__(16) float          s2sh[128], t2sh[128];
    __shared__ __align__(16) unsigned short ldsX[4][2][16 * XS_];  // per wave, per pt

    const int tid  = threadIdx.x;
    const int wave = tid >> 6;
    const int lane = tid & 63;
    const int l15  = lane & 15;
    const int quad = lane >> 4;

    unsigned short* XbA = &ldsX[wave][0][0];
    unsigned short* XbB = &ldsX[wave][1][0];

    // ---- stage BN scales + shifted biases, then W1'/W2' folded into LDS ----
    if (tid < 64) {
        const float s = g1[tid] * rsqrtf(v1[tid] + EPS_);
        s1sh[tid] = s;
        t1sh[tid] = (b1[tid] - m1[tid]) * s + be1[tid];
    }
    if (tid < 128) {
        const float s = g2[tid] * rsqrtf(v2[tid] + EPS_);
        s2sh[tid] = s;
        t2sh[tid] = (b2[tid] - m2[tid]) * s + be2[tid];
    }
    __syncthreads();
    for (int idx = tid; idx < 64 * 64; idx += 256) {     // w1[k][n] -> W1'[n][k]
        const int k = idx >> 6, n = idx & 63;
        ldsW1[n * WS_ + k] = (_Float16)(w1[idx] * s1sh[n]);
    }
    for (int idx = tid; idx < 64 * 128; idx += 256) {    // w2[k][n] -> W2'[n][k]
        const int k = idx >> 7, n = idx & 127;
        ldsW2[n * WS_ + k] = (_Float16)(w2[idx] * s2sh[n]);
    }
    __syncthreads();

    // ---- W0 BN-folded into register B-frags; bias via pad channel 67 ----
    // Feature k-order: [points 0..63, xyz_diff 64..66, BIAS 67 (=1.0), pad..95]
    h8 b0f[4][3];
#pragma unroll
    for (int nt = 0; nt < 4; ++nt) {
        const int ch = nt * 16 + l15;
        const float s = g0[ch] * rsqrtf(v0[ch] + EPS_);
        const float t0 = (b0[ch] - m0[ch]) * s + be0[ch];
#pragma unroll
        for (int kk = 0; kk < 3; ++kk) {
            h8 f;
#pragma unroll
            for (int j = 0; j < 8; ++j) {
                const int k = kk * 32 + quad * 8 + j;
                float wv = 0.f;
                if (k < 64)       wv = w0[(3 + k) * 64 + ch] * s;
                else if (k < 67)  wv = w0[(k - 64) * 64 + ch] * s;
                else if (k == 67) wv = t0;                 // bias via 1.0 channel
                f[j] = (_Float16)wv;
            }
            b0f[nt][kk] = f;
        }
    }

    // ---- main loop: 8 points per block iteration (2 per wave) ----
    const int g0i = blockIdx.x;
    const int pA0 = (g0i << 3) + (wave << 1);
    int nbA = nidx[(pA0 << 4) + l15];
    int nbB = nidx[((pA0 + 1) << 4) + l15];

    for (int grp = g0i; grp < NGRP_; grp += GRID_) {
        const int pA = (grp << 3) + (wave << 1);
        const int pB = pA + 1;
        const int gn = (grp + GRID_ < NGRP_) ? grp + GRID_ : grp;
        const int pAn = (gn << 3) + (wave << 1);

        // gather loads for both points (issue early)
        const size_t rowA = (size_t)(((pA >> 14) << 16) + nbA);
        const size_t rowB = (size_t)(((pB >> 14) << 16) + nbB);
        h8 qA0, qA1, qB0, qB1;
        if constexpr (PRE) {
            const _Float16* pwA = (const _Float16*)ptsv + (rowA << 6);
            const _Float16* pwB = (const _Float16*)ptsv + (rowB << 6);
            qA0 = *(const h8*)(pwA + quad * 8);
            qA1 = *(const h8*)(pwA + 32 + quad * 8);
            qB0 = *(const h8*)(pwB + quad * 8);
            qB1 = *(const h8*)(pwB + 32 + quad * 8);
        } else {
            const float* pwA = (const float*)ptsv + (rowA << 6);
            const float* pwB = (const float*)ptsv + (rowB << 6);
            f32x4 r0, r1, r2, r3;
            r0 = *(const f32x4*)(pwA + quad * 8);     r1 = *(const f32x4*)(pwA + quad * 8 + 4);
            r2 = *(const f32x4*)(pwA + 32 + quad * 8); r3 = *(const f32x4*)(pwA + 32 + quad * 8 + 4);
#pragma unroll
            for (int j = 0; j < 4; ++j) { qA0[j]=(_Float16)r0[j]; qA0[4+j]=(_Float16)r1[j];
                                          qA1[j]=(_Float16)r2[j]; qA1[4+j]=(_Float16)r3[j]; }
            r0 = *(const f32x4*)(pwB + quad * 8);     r1 = *(const f32x4*)(pwB + quad * 8 + 4);
            r2 = *(const f32x4*)(pwB + 32 + quad * 8); r3 = *(const f32x4*)(pwB + 32 + quad * 8 + 4);
#pragma unroll
            for (int j = 0; j < 4; ++j) { qB0[j]=(_Float16)r0[j]; qB0[4+j]=(_Float16)r1[j];
                                          qB1[j]=(_Float16)r2[j]; qB1[4+j]=(_Float16)r3[j]; }
        }
        const float mkA = vmask[(pA << 4) + l15];
        const float mkB = vmask[(pB << 4) + l15];
        const float* xgA = xyz + rowA * 3;
        const float* xgB = xyz + rowB * 3;
        const float xgA0 = xgA[0], xgA1 = xgA[1], xgA2 = xgA[2];
        const float xgB0 = xgB[0], xgB1 = xgB[1], xgB2 = xgB[2];
        const float* xsA = xyzs + (size_t)pA * 3;
        const float* xsB = xyzs + (size_t)pB * 3;
        const float xsA0 = xsA[0], xsA1 = xsA[1], xsA2 = xsA[2];
        const float xsB0 = xsB[0], xsB1 = xsB[1], xsB2 = xsB[2];

        // prefetch next iteration's neighbor indices
        const int nbAn = nidx[(pAn << 4) + l15];
        const int nbBn = nidx[((pAn + 1) << 4) + l15];

        if (mkA == 0.0f) { qA0 = (h8)(_Float16)0.f; qA1 = (h8)(_Float16)0.f; }
        if (mkB == 0.0f) { qB0 = (h8)(_Float16)0.f; qB1 = (h8)(_Float16)0.f; }
        h8 aA2 = (h8)(_Float16)0.f, aB2 = (h8)(_Float16)0.f;
        if (quad == 0) {
            aA2[0] = (_Float16)(xgA0 * mkA - xsA0);
            aA2[1] = (_Float16)(xgA1 * mkA - xsA1);
            aA2[2] = (_Float16)(xgA2 * mkA - xsA2);
            aA2[3] = (_Float16)1.0f;               // bias channel
            aB2[0] = (_Float16)(xgB0 * mkB - xsB0);
            aB2[1] = (_Float16)(xgB1 * mkB - xsB1);
            aB2[2] = (_Float16)(xgB2 * mkB - xsB2);
            aB2[3] = (_Float16)1.0f;
        }

        // ---- layer 0 (b0f const-indexed: keep fully unrolled) ----
#pragma unroll
        for (int nt = 0; nt < 4; ++nt) {
            f32x4 accA = {0.f,0.f,0.f,0.f}, accB = {0.f,0.f,0.f,0.f};
            accA = __builtin_amdgcn_mfma_f32_16x16x32_f16(qA0, b0f[nt][0], accA, 0, 0, 0);
            accA = __builtin_amdgcn_mfma_f32_16x16x32_f16(qA1, b0f[nt][1], accA, 0, 0, 0);
            accA = __builtin_amdgcn_mfma_f32_16x16x32_f16(aA2, b0f[nt][2], accA, 0, 0, 0);
            accB = __builtin_amdgcn_mfma_f32_16x16x32_f16(qB0, b0f[nt][0], accB, 0, 0, 0);
            accB = __builtin_amdgcn_mfma_f32_16x16x32_f16(qB1, b0f[nt][1], accB, 0, 0, 0);
            accB = __builtin_amdgcn_mfma_f32_16x16x32_f16(aB2, b0f[nt][2], accB, 0, 0, 0);
#pragma unroll
            for (int r = 0; r < 4; ++r) {
                const int xi = (quad * 4 + r) * XS_ + nt * 16 + l15;
                const _Float16 hA = (_Float16)fmaxf(accA[r], 0.f);
                const _Float16 hB = (_Float16)fmaxf(accB[r], 0.f);
                XbA[xi] = __builtin_bit_cast(unsigned short, hA);
                XbB[xi] = __builtin_bit_cast(unsigned short, hB);
            }
        }

        // ---- layer 1: W1 frags from LDS, shared across both points ----
        h8 xA0 = *(const h8*)(XbA + l15 * XS_ + quad * 8);
        h8 xA1 = *(const h8*)(XbA + l15 * XS_ + 32 + quad * 8);
        h8 xB0 = *(const h8*)(XbB + l15 * XS_ + quad * 8);
        h8 xB1 = *(const h8*)(XbB + l15 * XS_ + 32 + quad * 8);
#pragma unroll 2
        for (int nt = 0; nt < 4; ++nt) {
            const _Float16* wrow = ldsW1 + (nt * 16 + l15) * WS_;
            h8 wa = *(const h8*)(wrow + quad * 8);
            h8 wb = *(const h8*)(wrow + 32 + quad * 8);
            const float t1 = t1sh[nt * 16 + l15];
            f32x4 accA = {0.f,0.f,0.f,0.f}, accB = {0.f,0.f,0.f,0.f};
            accA = __builtin_amdgcn_mfma_f32_16x16x32_f16(xA0, wa, accA, 0, 0, 0);
            accA = __builtin_amdgcn_mfma_f32_16x16x32_f16(xA1, wb, accA, 0, 0, 0);
            accB = __builtin_amdgcn_mfma_f32_16x16x32_f16(xB0, wa, accB, 0, 0, 0);
            accB = __builtin_amdgcn_mfma_f32_16x16x32_f16(xB1, wb, accB, 0, 0, 0);
#pragma unroll
            for (int r = 0; r < 4; ++r) {
                const int xi = (quad * 4 + r) * XS_ + nt * 16 + l15;
                const _Float16 hA = (_Float16)fmaxf(accA[r] + t1, 0.f);
                const _Float16 hB = (_Float16)fmaxf(accB[r] + t1, 0.f);
                // same buffer: DS in-order per wave; x-frag reads issued above
                XbA[xi] = __builtin_bit_cast(unsigned short, hA);
                XbB[xi] = __builtin_bit_cast(unsigned short, hB);
            }
        }

        // ---- layer 2: W2 frags from LDS + K-maxpool + inline stores ----
        h8 yA0 = *(const h8*)(XbA + l15 * XS_ + quad * 8);
        h8 yA1 = *(const h8*)(XbA + l15 * XS_ + 32 + quad * 8);
        h8 yB0 = *(const h8*)(XbB + l15 * XS_ + quad * 8);
        h8 yB1 = *(const h8*)(XbB + l15 * XS_ + 32 + quad * 8);
        float* obA = out + ((size_t)pA << 7);
        float* obB = out + ((size_t)pB << 7);
#pragma unroll 2
        for (int nt = 0; nt < 8; ++nt) {
            const _Float16* wrow = ldsW2 + (nt * 16 + l15) * WS_;
            h8 wa = *(const h8*)(wrow + quad * 8);
            h8 wb = *(const h8*)(wrow + 32 + quad * 8);
            const float t2 = t2sh[nt * 16 + l15];
            f32x4 accA = {0.f,0.f,0.f,0.f}, accB = {0.f,0.f,0.f,0.f};
            accA = __builtin_amdgcn_mfma_f32_16x16x32_f16(yA0, wa, accA, 0, 0, 0);
            accA = __builtin_amdgcn_mfma_f32_16x16x32_f16(yA1, wb, accA, 0, 0, 0);
            accB = __builtin_amdgcn_mfma_f32_16x16x32_f16(yB0, wa, accB, 0, 0, 0);
            accB = __builtin_amdgcn_mfma_f32_16x16x32_f16(yB1, wb, accB, 0, 0, 0);
            float vA = fmaxf(fmaxf(accA[0], accA[1]), fmaxf(accA[2], accA[3])) + t2;
            float vB = fmaxf(fmaxf(accB[0], accB[1]), fmaxf(accB[2], accB[3])) + t2;
            vA = fmaxf(vA, 0.f);  vB = fmaxf(vB, 0.f);    // relu(max)=max(relu)
            vA = fmaxf(vA, __shfl_xor(vA, 16, 64));
            vA = fmaxf(vA, __shfl_xor(vA, 32, 64));
            vB = fmaxf(vB, __shfl_xor(vB, 16, 64));
            vB = fmaxf(vB, __shfl_xor(vB, 32, 64));
            if (quad == 0) {
                obA[nt * 16 + l15]            = vA;
                obA[OUTHALF_ + nt * 16 + l15] = vA;
                obB[nt * 16 + l15]            = vB;
                obB[OUTHALF_ + nt * 16 + l15] = vB;
            }
        }

        nbA = nbAn; nbB = nbBn;
    }
}

extern "C" void kernel_launch(void* const* d_in, const int* in_sizes, int n_in,
                              void* d_out, int out_size, void* d_ws, size_t ws_size,
                              hipStream_t stream) {
    const float* xyz   = (const float*)d_in[0];
    const float* pts   = (const float*)d_in[1];
    const float* xyzs  = (const float*)d_in[2];
    const int*   nidx  = (const int*)d_in[3];
    const float* vmask = (const float*)d_in[4];
    const float *w0 = (const float*)d_in[5],  *b0 = (const float*)d_in[6],
                *g0 = (const float*)d_in[7],  *be0 = (const float*)d_in[8],
                *m0 = (const float*)d_in[9],  *v0 = (const float*)d_in[10];
    const float *w1 = (const float*)d_in[11], *b1 = (const float*)d_in[12],
                *g1 = (const float*)d_in[13], *be1 = (const float*)d_in[14],
                *m1 = (const float*)d_in[15], *v1 = (const float*)d_in[16];
    const float *w2 = (const float*)d_in[17], *b2 = (const float*)d_in[18],
                *g2 = (const float*)d_in[19], *be2 = (const float*)d_in[20],
                *m2 = (const float*)d_in[21], *v2 = (const float*)d_in[22];
    float* outp = (float*)d_out;

    const size_t PTS_ELEMS = 16777216ull;           // 4*65536*64
    if (ws_size >= PTS_ELEMS * sizeof(_Float16)) {
        _Float16* ptsh = (_Float16*)d_ws;
        cvt_pts_kernel<<<dim3(8192), dim3(256), 0, stream>>>(pts, ptsh);
        pnsa_main<true><<<dim3(GRID_), dim3(256), 0, stream>>>(
            xyz, (const void*)ptsh, xyzs, nidx, vmask,
            w0, b0, g0, be0, m0, v0,
            w1, b1, g1, be1, m1, v1,
            w2, b2, g2, be2, m2, v2, outp);
    } else {
        pnsa_main<false><<<dim3(GRID_), dim3(256), 0, stream>>>(
            xyz, (const void*)pts, xyzs, nidx, vmask,
            w0, b0, g0, be0, m0, v0,
            w1, b1, g1, be1, m1, v1,
            w2, b2, g2, be2, m2, v2, outp);
    }
}